// Round 5
// baseline (1305.367 us; speedup 1.0000x reference)
//
#include <hip/hip_runtime.h>
#include <hip/hip_bf16.h>

// Problem constants
#define B_   32
#define C_   256
#define HW_  1024
#define N_   32768      // B_*HW_
#define M_   2000
#define MP_  2048       // M padded (rows >= 2000 are zero)
#define K_   256
#define TN   32         // pixels per workgroup -> grid 1024
#define QPITCH 272      // halves; q tile [32][272]
#define APITCH 2068     // halves; att tile [32][2068]

typedef __attribute__((ext_vector_type(8))) _Float16 f16x8;
typedef __attribute__((ext_vector_type(8))) short bf16x8;
typedef __attribute__((ext_vector_type(4))) float f32x4;

#define LDS_ATT_BYTES (TN * APITCH * 2)        // 132352 (q tiles alias the front)
#define LDS_SP_OFF    LDS_ATT_BYTES            // float Sp[8][32]
#define LDS_THR_OFF   (LDS_SP_OFF + 8 * 32 * 4)
#define LDS_INV_OFF   (LDS_THR_OFF + 32 * 4)
#define LDS_TOTAL     (LDS_INV_OFF + 32 * 4)   // 133632 B

#define CAP_ENTRIES   (1536 * 1024)            // 12 MB of (u32 key, f32 p) pairs

// ---------------- prep kernels ----------------

// mem*64 -> fp16 hi/lo split, [MP_][K_], zero-padded rows (GEMM1 B, K-major)
__global__ void prep_memS_kernel(const float* __restrict__ mem,
                                 _Float16* __restrict__ mh,
                                 _Float16* __restrict__ ml) {
  int m = blockIdx.x;           // 0..2047
  int c = threadIdx.x;          // 0..255
  float v = (m < M_) ? mem[m * K_ + c] * 64.0f : 0.0f;
  _Float16 h = (_Float16)v;
  mh[m * K_ + c] = h;
  ml[m * K_ + c] = (_Float16)(v - (float)h);
}

// memT[c][m] bf16, zero-padded m>=2000 (GEMM2 B operand, K(=m)-major)
__global__ void prep_memT_kernel(const float* __restrict__ mem,
                                 __hip_bfloat16* __restrict__ memT) {
  __shared__ float t[32][33];
  int m0 = blockIdx.x * 32;     // 64 blocks
  int c0 = blockIdx.y * 32;     // 8 blocks
  int li = threadIdx.x >> 5;    // 0..7
  int lj = threadIdx.x & 31;
#pragma unroll
  for (int it = 0; it < 4; ++it) {
    int m = li + it * 8;
    t[m][lj] = (m0 + m < M_) ? mem[(m0 + m) * K_ + c0 + lj] : 0.0f;
  }
  __syncthreads();
#pragma unroll
  for (int it = 0; it < 4; ++it) {
    int c = li + it * 8;
    memT[(size_t)(c0 + c) * MP_ + m0 + lj] = __float2bfloat16(t[lj][c]);
  }
}

// ---------------- fused main kernel ----------------
// Per WG (32 pixel-rows): 3-pass fp16-split GEMM1 (round-3 numerics) ->
// fp32 logits in MFMA accs -> e=exp, S -> keep iff e > λ·S -> sparse append
// of kept (n,m,p) to a global list (att is ~3/2000 dense) -> bf16 GEMM2 -> y.
// Outer k-loops are ROLLED (small body, I$-resident); acc indexing static.
__global__ __launch_bounds__(512, 2) void memae_main_kernel(
    const float* __restrict__ x,
    const _Float16* __restrict__ mh,
    const _Float16* __restrict__ ml,
    const __hip_bfloat16* __restrict__ memT,
    float* __restrict__ y,
    uint2* __restrict__ entries,
    unsigned int* __restrict__ cnt) {
  extern __shared__ char smem[];
  _Float16* qhi = (_Float16*)smem;                       // [32][QPITCH]
  _Float16* qlo = (_Float16*)(smem + TN * QPITCH * 2);   // [32][QPITCH]
  __hip_bfloat16* att = (__hip_bfloat16*)smem;           // [32][APITCH] (aliases q)
  float* Sp   = (float*)(smem + LDS_SP_OFF);             // [8][32]
  float* thrL = (float*)(smem + LDS_THR_OFF);            // [32]
  float* invS = (float*)(smem + LDS_INV_OFF);            // [32]

  const int tid   = threadIdx.x;
  const int lane  = tid & 63;
  const int wave  = tid >> 6;        // 0..7
  const int row16 = lane & 15;
  const int quad  = lane >> 4;       // 0..3

  const int n0  = blockIdx.x * TN;
  const int b   = n0 >> 10;
  const int hw0 = n0 & 1023;

  // ---- stage q tile: read x[b][c][hw0..hw0+31], split fp32 -> f16 hi+lo ----
  {
    int c = tid >> 1;                 // 0..255
    int h = tid & 1;                  // which 16 hw's
    const float4* xp = (const float4*)(x + ((size_t)b * C_ + c) * HW_ + hw0 + h * 16);
    float4 v0 = xp[0], v1 = xp[1], v2 = xp[2], v3 = xp[3];
    float v[16] = {v0.x, v0.y, v0.z, v0.w, v1.x, v1.y, v1.z, v1.w,
                   v2.x, v2.y, v2.z, v2.w, v3.x, v3.y, v3.z, v3.w};
#pragma unroll
    for (int j = 0; j < 16; ++j) {
      int n = h * 16 + j;
      _Float16 fh = (_Float16)v[j];
      qhi[n * QPITCH + c] = fh;
      qlo[n * QPITCH + c] = (_Float16)(v[j] - (float)fh);
    }
  }
  __syncthreads();

  // ---- GEMM1 (3-pass split): 64*logit into acc. wave owns m in [wave*256,+256) ----
  f32x4 acc[16][2];
#pragma unroll
  for (int mt = 0; mt < 16; ++mt)
#pragma unroll
    for (int nt = 0; nt < 2; ++nt) acc[mt][nt] = (f32x4){0.f, 0.f, 0.f, 0.f};

  {
    const int abase = row16 * QPITCH + quad * 8;
    const int bbase = (wave * 256 + row16) * K_ + quad * 8;
#pragma unroll 1
    for (int ks = 0; ks < 8; ++ks) {            // ROLLED: small I$ footprint
      f16x8 ah0 = *(const f16x8*)(qhi + abase + ks * 32);
      f16x8 ah1 = *(const f16x8*)(qhi + abase + 16 * QPITCH + ks * 32);
      f16x8 al0 = *(const f16x8*)(qlo + abase + ks * 32);
      f16x8 al1 = *(const f16x8*)(qlo + abase + 16 * QPITCH + ks * 32);
#pragma unroll
      for (int g = 0; g < 4; ++g) {
        f16x8 bh[4], bl[4];
#pragma unroll
        for (int i = 0; i < 4; ++i) {
          const int moff = bbase + (g * 4 + i) * 16 * K_ + ks * 32;
          bh[i] = *(const f16x8*)(mh + moff);
          bl[i] = *(const f16x8*)(ml + moff);
        }
#pragma unroll
        for (int i = 0; i < 4; ++i) {
          const int mt = g * 4 + i;             // static index
          acc[mt][0] = __builtin_amdgcn_mfma_f32_16x16x32_f16(ah0, bh[i], acc[mt][0], 0, 0, 0);
          acc[mt][1] = __builtin_amdgcn_mfma_f32_16x16x32_f16(ah1, bh[i], acc[mt][1], 0, 0, 0);
          acc[mt][0] = __builtin_amdgcn_mfma_f32_16x16x32_f16(al0, bh[i], acc[mt][0], 0, 0, 0);
          acc[mt][1] = __builtin_amdgcn_mfma_f32_16x16x32_f16(al1, bh[i], acc[mt][1], 0, 0, 0);
          acc[mt][0] = __builtin_amdgcn_mfma_f32_16x16x32_f16(ah0, bl[i], acc[mt][0], 0, 0, 0);
          acc[mt][1] = __builtin_amdgcn_mfma_f32_16x16x32_f16(ah1, bl[i], acc[mt][1], 0, 0, 0);
        }
      }
    }
  }

  // ---- e = exp(logit) in-place; per-row sum S (shuffle + LDS reduce) ----
  float rp[2][4] = {{0.f, 0.f, 0.f, 0.f}, {0.f, 0.f, 0.f, 0.f}};
#pragma unroll
  for (int mt = 0; mt < 16; ++mt) {
    const bool pad = (wave == 7) && (mt >= 13);   // m >= 2000
#pragma unroll
    for (int nt = 0; nt < 2; ++nt)
#pragma unroll
      for (int r = 0; r < 4; ++r) {
        float e = pad ? 0.f : __expf(acc[mt][nt][r] * 0.015625f);  // *2^-6 exact
        acc[mt][nt][r] = e;
        rp[nt][r] += e;
      }
  }
#pragma unroll
  for (int off = 8; off >= 1; off >>= 1)
#pragma unroll
    for (int nt = 0; nt < 2; ++nt)
#pragma unroll
      for (int r = 0; r < 4; ++r) rp[nt][r] += __shfl_xor(rp[nt][r], off, 16);
  if (row16 == 0) {
#pragma unroll
    for (int nt = 0; nt < 2; ++nt)
#pragma unroll
      for (int r = 0; r < 4; ++r) Sp[wave * 32 + nt * 16 + quad * 4 + r] = rp[nt][r];
  }
  __syncthreads();

  if (tid < 32) {
    float s = 0.f;
#pragma unroll
    for (int w = 0; w < 8; ++w) s += Sp[w * 32 + tid];
    thrL[tid] = 0.0025f * s;          // keep iff e > lambda * S
  }
  __syncthreads();

  // ---- decisions (fp32): kept e stays in acc; bf16 copy to LDS for GEMM2 ----
  float th[2][4], s2[2][4];
#pragma unroll
  for (int nt = 0; nt < 2; ++nt)
#pragma unroll
    for (int r = 0; r < 4; ++r) {
      th[nt][r] = thrL[nt * 16 + quad * 4 + r];
      s2[nt][r] = 0.f;
    }
#pragma unroll
  for (int mt = 0; mt < 16; ++mt) {
    const int m = wave * 256 + mt * 16 + row16;
#pragma unroll
    for (int nt = 0; nt < 2; ++nt)
#pragma unroll
      for (int r = 0; r < 4; ++r) {
        float e = acc[mt][nt][r];
        float v = (e > th[nt][r]) ? e : 0.f;
        acc[mt][nt][r] = v;
        s2[nt][r] += v;
        att[(nt * 16 + quad * 4 + r) * APITCH + m] = __float2bfloat16(v);
      }
  }
#pragma unroll
  for (int off = 8; off >= 1; off >>= 1)
#pragma unroll
    for (int nt = 0; nt < 2; ++nt)
#pragma unroll
      for (int r = 0; r < 4; ++r) s2[nt][r] += __shfl_xor(s2[nt][r], off, 16);
  if (row16 == 0) {
#pragma unroll
    for (int nt = 0; nt < 2; ++nt)
#pragma unroll
      for (int r = 0; r < 4; ++r) Sp[wave * 32 + nt * 16 + quad * 4 + r] = s2[nt][r];
  }
  __syncthreads();

  if (tid < 32) {
    float s = 0.f;
#pragma unroll
    for (int w = 0; w < 8; ++w) s += Sp[w * 32 + tid];
    invS[tid] = (s > 0.f) ? (1.0f / s) : 0.f;   // ref: denom=max(sum,1e-12)
  }
  __syncthreads();

  float inv[2][4];
#pragma unroll
  for (int nt = 0; nt < 2; ++nt)
#pragma unroll
    for (int r = 0; r < 4; ++r) inv[nt][r] = invS[nt * 16 + quad * 4 + r];

  // ---- sparse append of kept attention entries (att is ~3/2000 dense) ----
#pragma unroll
  for (int mt = 0; mt < 16; ++mt) {
    const int m = wave * 256 + mt * 16 + row16;
#pragma unroll
    for (int nt = 0; nt < 2; ++nt)
#pragma unroll
      for (int r = 0; r < 4; ++r) {
        float v = acc[mt][nt][r];
        if (v > 0.f) {
          unsigned int idx = atomicAdd(cnt, 1u);
          if (idx < (unsigned int)CAP_ENTRIES) {
            uint2 ent;
            ent.x = ((unsigned int)(n0 + nt * 16 + quad * 4 + r) << 11) | (unsigned int)m;
            ent.y = __float_as_uint(v * inv[nt][r]);
            entries[idx] = ent;
          }
        }
      }
  }

  // ---- GEMM2: y = (e @ mem) * invS. wave w owns c in [w*32, w*32+32) ----
  {
    f32x4 o[2][2];
#pragma unroll
    for (int i = 0; i < 2; ++i)
#pragma unroll
      for (int j2 = 0; j2 < 2; ++j2) o[i][j2] = (f32x4){0.f, 0.f, 0.f, 0.f};

    const __hip_bfloat16* bt0 = memT + (size_t)(wave * 32 + row16) * MP_ + quad * 8;
    const __hip_bfloat16* bt1 = bt0 + (size_t)16 * MP_;
    const __hip_bfloat16* a0p = att + row16 * APITCH + quad * 8;
    const __hip_bfloat16* a1p = a0p + 16 * APITCH;

#pragma unroll 1
    for (int ch = 0; ch < 4; ++ch) {            // ROLLED outer
#pragma unroll
      for (int kk = 0; kk < 16; ++kk) {
        const int ks = ch * 16 + kk;
        bf16x8 a0 = *(const bf16x8*)(a0p + ks * 32);
        bf16x8 a1 = *(const bf16x8*)(a1p + ks * 32);
        bf16x8 b0 = *(const bf16x8*)(bt0 + ks * 32);
        bf16x8 b1 = *(const bf16x8*)(bt1 + ks * 32);
        o[0][0] = __builtin_amdgcn_mfma_f32_16x16x32_bf16(a0, b0, o[0][0], 0, 0, 0);
        o[0][1] = __builtin_amdgcn_mfma_f32_16x16x32_bf16(a0, b1, o[0][1], 0, 0, 0);
        o[1][0] = __builtin_amdgcn_mfma_f32_16x16x32_bf16(a1, b0, o[1][0], 0, 0, 0);
        o[1][1] = __builtin_amdgcn_mfma_f32_16x16x32_bf16(a1, b1, o[1][1], 0, 0, 0);
      }
    }

    float* yb = y + (size_t)b * C_ * HW_ + hw0;
#pragma unroll
    for (int nt = 0; nt < 2; ++nt) {
#pragma unroll
      for (int ct = 0; ct < 2; ++ct) {
        int c = wave * 32 + ct * 16 + row16;
        int nbase = nt * 16 + quad * 4;
        float4 v;
        v.x = o[nt][ct][0] * inv[nt][0];
        v.y = o[nt][ct][1] * inv[nt][1];
        v.z = o[nt][ct][2] * inv[nt][2];
        v.w = o[nt][ct][3] * inv[nt][3];
        *(float4*)(yb + (size_t)c * HW_ + nbase) = v;
      }
    }
  }
}

// ---------------- scatter kernel: att_out[b][m][hw] = p for kept entries ----
__global__ void scatter_kernel(const uint2* __restrict__ entries,
                               const unsigned int* __restrict__ cnt,
                               float* __restrict__ att_out) {
  unsigned int t = blockIdx.x * 256 + threadIdx.x;
  unsigned int n = *cnt;
  if (n > (unsigned int)CAP_ENTRIES) n = (unsigned int)CAP_ENTRIES;
  if (t < n) {
    uint2 e = entries[t];
    unsigned int ng = e.x >> 11;
    unsigned int m  = e.x & 2047u;
    unsigned int b  = ng >> 10;
    unsigned int hw = ng & 1023u;
    att_out[(size_t)b * M_ * HW_ + (size_t)m * HW_ + hw] = __uint_as_float(e.y);
  }
}

// ---------------- host ----------------
extern "C" void kernel_launch(void* const* d_in, const int* in_sizes, int n_in,
                              void* d_out, int out_size, void* d_ws, size_t ws_size,
                              hipStream_t stream) {
  const float* x   = (const float*)d_in[0];      // [32,256,32,32]
  const float* mem = (const float*)d_in[1];      // [2000,256]
  float* y       = (float*)d_out;                              // 8388608 floats
  float* att_out = (float*)d_out + (size_t)B_ * C_ * HW_;      // 65536000 floats

  char* ws = (char*)d_ws;
  _Float16* mh = (_Float16*)ws;                                        // 1 MB
  _Float16* ml = (_Float16*)(ws + (size_t)1024 * 1024);                // 1 MB
  __hip_bfloat16* memT = (__hip_bfloat16*)(ws + (size_t)2 * 1024 * 1024);  // 1 MB
  uint2* entries = (uint2*)(ws + (size_t)3 * 1024 * 1024);             // 12 MB
  unsigned int* cnt = (unsigned int*)(ws + (size_t)15 * 1024 * 1024 + 512 * 1024);

  (void)hipFuncSetAttribute((const void*)memae_main_kernel,
                            hipFuncAttributeMaxDynamicSharedMemorySize, LDS_TOTAL);

  // zero att output region (sparse scatter fills the kept entries) + counter
  hipMemsetAsync(att_out, 0, (size_t)B_ * M_ * HW_ * sizeof(float), stream);
  hipMemsetAsync(cnt, 0, sizeof(unsigned int), stream);

  prep_memS_kernel<<<dim3(MP_), dim3(K_), 0, stream>>>(mem, mh, ml);
  prep_memT_kernel<<<dim3(MP_ / 32, K_ / 32), dim3(256), 0, stream>>>(mem, memT);
  memae_main_kernel<<<dim3(N_ / TN), dim3(512), LDS_TOTAL, stream>>>(
      x, mh, ml, memT, y, entries, cnt);
  scatter_kernel<<<dim3(CAP_ENTRIES / 256), dim3(256), 0, stream>>>(
      entries, cnt, att_out);
}

// Round 7
// 664.448 us; speedup vs baseline: 1.9646x; 1.9646x over previous
//
#include <hip/hip_runtime.h>
#include <hip/hip_bf16.h>

// Problem constants
#define B_   32
#define C_   256
#define HW_  1024
#define N_   32768      // B_*HW_
#define M_   2000
#define MP_  2048       // M padded (rows >= 2000 are zero)
#define K_   256

typedef __attribute__((ext_vector_type(8))) _Float16 f16x8;
typedef __attribute__((ext_vector_type(4))) float f32x4;

#define CAP_ENTRIES (256 * 1024)
#define KCAP 32

// ---------------- prep kernels ----------------

// mem*64 -> fp16 hi/lo split, [MP_][K_], zero-padded rows (GEMM1 B, K-major)
__global__ void prep_memS_kernel(const float* __restrict__ mem,
                                 _Float16* __restrict__ mh,
                                 _Float16* __restrict__ ml) {
  int m = blockIdx.x;           // 0..2047
  int c = threadIdx.x;          // 0..255
  float v = (m < M_) ? mem[m * K_ + c] * 64.0f : 0.0f;
  _Float16 h = (_Float16)v;
  mh[m * K_ + c] = h;
  ml[m * K_ + c] = (_Float16)(v - (float)h);
}

// q[n][c] f16 hi/lo from x[b][c][hw] (tile transpose through LDS).
// qhi/qlo live in the y OUTPUT region (dead until finalize) - ws stays small.
__global__ void prep_q_kernel(const float* __restrict__ x,
                              _Float16* __restrict__ qhi,
                              _Float16* __restrict__ qlo) {
  __shared__ float t[32][33];
  int hw0 = blockIdx.x * 32;    // 32 blocks
  int c0  = blockIdx.y * 32;    // 8 blocks
  int b   = blockIdx.z;         // 32 blocks
  int li = threadIdx.x >> 5;
  int lj = threadIdx.x & 31;
  const float* xb = x + (size_t)b * C_ * HW_;
#pragma unroll
  for (int it = 0; it < 4; ++it) {
    int c = li + it * 8;
    t[c][lj] = xb[(size_t)(c0 + c) * HW_ + hw0 + lj];
  }
  __syncthreads();
#pragma unroll
  for (int it = 0; it < 4; ++it) {
    int n = li + it * 8;
    float v = t[lj][n];
    _Float16 h = (_Float16)v;
    size_t idx = (size_t)(b * HW_ + hw0 + n) * K_ + c0 + lj;
    qhi[idx] = h;
    qlo[idx] = (_Float16)(v - (float)h);
  }
}

// ---------------- K1: 3-pass fp16-split GEMM1 (m97 structure) ----------------
// 128n x 128m tile per WG, virtual K = 768 (hh, lh, hl), BK=64,
// global_load_lds width-16 staging. Epilogue: e=exp(64*logit * 2^-6) ->
// fp32 store to eb[n][2000], per-row partial sums atomicAdd into S[n].
__global__ __launch_bounds__(256, 3) void gemm1_kernel(
    const _Float16* __restrict__ qhi, const _Float16* __restrict__ qlo,
    const _Float16* __restrict__ mh, const _Float16* __restrict__ ml,
    float* __restrict__ eb, float* __restrict__ S) {
  __shared__ _Float16 As[128 * 64];   // 16 KB
  __shared__ _Float16 Bs[128 * 64];   // 16 KB

  const int tid   = threadIdx.x;
  const int lane  = tid & 63;
  const int wave  = tid >> 6;        // 0..3
  const int row16 = lane & 15;
  const int quad  = lane >> 4;
  const int wr    = wave >> 1;       // n-half of wave
  const int wc    = wave & 1;        // m-half of wave
  const int m0 = blockIdx.x * 128;
  const int n0 = blockIdx.y * 128;

  f32x4 acc[4][4];
#pragma unroll
  for (int i = 0; i < 4; ++i)
#pragma unroll
    for (int j = 0; j < 4; ++j) acc[i][j] = (f32x4){0.f, 0.f, 0.f, 0.f};

  const int srow = tid >> 3;          // 0..31 (staging row within 32-row slab)
  const int scol = (tid & 7) * 8;     // halves; dst LDS addr = lane*16B (wave-uniform+lane pattern)

  for (int ch = 0; ch < 12; ++ch) {
    const int ph = ch >> 2;           // 0: hh, 1: lh, 2: hl
    const int k0 = (ch & 3) * 64;
    const _Float16* Ag = (ph == 1) ? qlo : qhi;
    const _Float16* Bg = (ph == 2) ? ml : mh;

    // stage A,B tiles: 4 + 4 global_load_lds dwordx4 per thread
#pragma unroll
    for (int i = 0; i < 4; ++i) {
      int row = i * 32 + srow;
      const _Float16* srcA = Ag + (size_t)(n0 + row) * K_ + k0 + scol;
      __builtin_amdgcn_global_load_lds(
          (const __attribute__((address_space(1))) unsigned int*)srcA,
          (__attribute__((address_space(3))) unsigned int*)(As + row * 64 + scol),
          16, 0, 0);
    }
#pragma unroll
    for (int i = 0; i < 4; ++i) {
      int row = i * 32 + srow;
      const _Float16* srcB = Bg + (size_t)(m0 + row) * K_ + k0 + scol;
      __builtin_amdgcn_global_load_lds(
          (const __attribute__((address_space(1))) unsigned int*)srcB,
          (__attribute__((address_space(3))) unsigned int*)(Bs + row * 64 + scol),
          16, 0, 0);
    }
    __syncthreads();

#pragma unroll
    for (int kk = 0; kk < 2; ++kk) {
      f16x8 af[4], bf[4];
#pragma unroll
      for (int t = 0; t < 4; ++t)
        af[t] = *(const f16x8*)(As + (wr * 64 + t * 16 + row16) * 64 + kk * 32 + quad * 8);
#pragma unroll
      for (int t = 0; t < 4; ++t)
        bf[t] = *(const f16x8*)(Bs + (wc * 64 + t * 16 + row16) * 64 + kk * 32 + quad * 8);
#pragma unroll
      for (int i = 0; i < 4; ++i)
#pragma unroll
        for (int j = 0; j < 4; ++j)
          acc[i][j] = __builtin_amdgcn_mfma_f32_16x16x32_f16(af[i], bf[j], acc[i][j], 0, 0, 0);
    }
    __syncthreads();
  }

  // epilogue: exp, store e, per-row partial sums
  const int mbase = m0 + wc * 64 + row16;
#pragma unroll
  for (int i = 0; i < 4; ++i) {
    float rs[4] = {0.f, 0.f, 0.f, 0.f};
    const int nb = n0 + wr * 64 + i * 16 + quad * 4;
#pragma unroll
    for (int j = 0; j < 4; ++j) {
      const int mg = mbase + j * 16;
      const bool ok = (mg < M_);
#pragma unroll
      for (int r = 0; r < 4; ++r) {
        float e = ok ? __expf(acc[i][j][r] * 0.015625f) : 0.f;
        if (ok) eb[(size_t)(nb + r) * M_ + mg] = e;
        rs[r] += e;
      }
    }
#pragma unroll
    for (int r = 0; r < 4; ++r) {
#pragma unroll
      for (int off = 8; off >= 1; off >>= 1) rs[r] += __shfl_xor(rs[r], off, 16);
      if (row16 == 0) atomicAdd(&S[nb + r], rs[r]);
    }
  }
}

// ---------------- K3: threshold + sparse GEMM2 + entry list ----------------
// Per WG: 32 pixel rows. Stream fp32 e, keep iff e > lambda*S (softmax denom
// cancels), collect kept (m,p) in LDS (~2/row), S2 = sum kept. Then
// y[c][hw] = sum_kept p*mem[m][c] / S2 (sparse), and append normalized
// entries for the att scatter.
__global__ __launch_bounds__(512) void finalize_kernel(
    const float* __restrict__ eb, const float* __restrict__ S,
    const float* __restrict__ mem, float* __restrict__ y,
    uint2* __restrict__ entries, unsigned int* __restrict__ cnt) {
  __shared__ unsigned int kcnt[32];
  __shared__ unsigned int km[32][KCAP];
  __shared__ float kp[32][KCAP];
  __shared__ float kinv[32];

  const int tid  = threadIdx.x;
  const int lane = tid & 63;
  const int wave = tid >> 6;       // 0..7
  const int n0 = blockIdx.x * 32;

  // phase 1: threshold scan (4 rows per wave)
#pragma unroll 1
  for (int rr = 0; rr < 4; ++rr) {
    const int rw = wave * 4 + rr;
    const int n = n0 + rw;
    const float thr = 0.0025f * S[n];
    const float* er = eb + (size_t)n * M_;
    float s2 = 0.f;
    unsigned int c = 0;
#pragma unroll 1
    for (int i = 0; i < 32; ++i) {
      const int j = i * 64 + lane;
      float v = (j < M_) ? er[j] : 0.f;
      unsigned long long mask = __ballot(v > thr);
      while (mask) {
        const int src = __builtin_ctzll(mask);
        mask &= mask - 1;
        const float p = __shfl(v, src, 64);
        if (lane == 0 && c < (unsigned)KCAP) {
          km[rw][c] = (unsigned)(i * 64 + src);
          kp[rw][c] = p;
        }
        ++c;
        s2 += p;
      }
    }
    if (lane == 0) {
      kcnt[rw] = (c < (unsigned)KCAP) ? c : (unsigned)KCAP;
      kinv[rw] = (s2 > 0.f) ? (1.0f / s2) : 0.f;
    }
  }
  __syncthreads();

  // append normalized entries for scatter
  if (tid < 32) {
    const int n = n0 + tid;
    const unsigned int kc = kcnt[tid];
    if (kc) {
      unsigned int base = atomicAdd(cnt, kc);
      for (unsigned int k = 0; k < kc && base + k < (unsigned)CAP_ENTRIES; ++k) {
        uint2 e;
        e.x = ((unsigned)n << 11) | km[tid][k];
        e.y = __float_as_uint(kp[tid][k] * kinv[tid]);
        entries[base + k] = e;
      }
    }
  }

  // phase 2: sparse y. thread covers (c = ci*16 + tid>>5, hw row = tid&31)
  {
    const int hwL = tid & 31;
    const int cq  = tid >> 5;        // 0..15
    const int n = n0 + hwL;
    const int b = n >> 10;
    const int hw = n & 1023;
    const unsigned int kc = kcnt[hwL];
    const float inv = kinv[hwL];
    float* yb = y + (size_t)b * C_ * HW_ + hw;
#pragma unroll 1
    for (int ci = 0; ci < 16; ++ci) {
      const int c = ci * 16 + cq;
      float yv = 0.f;
      for (unsigned int k = 0; k < kc; ++k)
        yv += kp[hwL][k] * mem[(size_t)km[hwL][k] * K_ + c];
      yb[(size_t)c * HW_] = yv * inv;
    }
  }
}

// ---------------- scatter: att_out[b][m][hw] = p for kept entries ----------
__global__ void scatter_kernel(const uint2* __restrict__ entries,
                               const unsigned int* __restrict__ cnt,
                               float* __restrict__ att_out) {
  unsigned int t = blockIdx.x * 256 + threadIdx.x;
  unsigned int n = *cnt;
  if (n > (unsigned int)CAP_ENTRIES) n = (unsigned int)CAP_ENTRIES;
  if (t < n) {
    uint2 e = entries[t];
    unsigned int ng = e.x >> 11;
    unsigned int m  = e.x & 2047u;
    unsigned int b  = ng >> 10;
    unsigned int hw = ng & 1023u;
    att_out[(size_t)b * M_ * HW_ + (size_t)m * HW_ + hw] = __uint_as_float(e.y);
  }
}

// ---------------- host ----------------
extern "C" void kernel_launch(void* const* d_in, const int* in_sizes, int n_in,
                              void* d_out, int out_size, void* d_ws, size_t ws_size,
                              hipStream_t stream) {
  const float* x   = (const float*)d_in[0];      // [32,256,32,32]
  const float* mem = (const float*)d_in[1];      // [2000,256]
  float* y       = (float*)d_out;                              // 8388608 floats (33.55 MB)
  float* att_out = (float*)d_out + (size_t)B_ * C_ * HW_;      // 65536000 floats (262 MB)

  // q hi/lo (16 MB each) alias the y output region: written by prep_q, read
  // by gemm1, dead before finalize writes y. Keeps d_ws usage ~5 MB.
  _Float16* qhi = (_Float16*)y;
  _Float16* qlo = (_Float16*)((char*)y + (size_t)16 * 1024 * 1024);

  char* ws = (char*)d_ws;
  _Float16* mh  = (_Float16*)ws;                                   // 1 MB
  _Float16* ml  = (_Float16*)(ws + (size_t)1024 * 1024);           // 1 MB
  float*    S   = (float*)(ws + (size_t)2 * 1024 * 1024);          // 128 KB
  uint2* entries = (uint2*)(ws + (size_t)3 * 1024 * 1024);         // 2 MB
  unsigned int* cnt = (unsigned int*)(ws + (size_t)5 * 1024 * 1024);

  // e scratch aliases the att output region: [N_][M_] fp32 = exactly att bytes
  float* eb = att_out;

  prep_memS_kernel<<<dim3(MP_), dim3(K_), 0, stream>>>(mem, mh, ml);
  prep_q_kernel<<<dim3(HW_ / 32, C_ / 32, B_), dim3(256), 0, stream>>>(x, qhi, qlo);
  hipMemsetAsync(S, 0, (size_t)N_ * sizeof(float), stream);
  hipMemsetAsync(cnt, 0, sizeof(unsigned int), stream);

  gemm1_kernel<<<dim3(MP_ / 128, N_ / 128), dim3(256), 0, stream>>>(
      qhi, qlo, mh, ml, eb, S);
  finalize_kernel<<<dim3(N_ / 32), dim3(512), 0, stream>>>(
      eb, S, mem, y, entries, cnt);
  hipMemsetAsync(att_out, 0, (size_t)B_ * M_ * HW_ * sizeof(float), stream);
  scatter_kernel<<<dim3(CAP_ENTRIES / 256), dim3(256), 0, stream>>>(
      entries, cnt, att_out);
}